// Round 5
// baseline (178.422 us; speedup 1.0000x reference)
//
#include <hip/hip_runtime.h>
#include <hip/hip_bf16.h>

// B=8, N=4096, L=256, E=64, D=128, Q4=32
#define B_ 8
#define N_ 4096
#define L_ 256
#define E_ 64
#define D_ 128

typedef const float* fp;

__device__ __forceinline__ float W_at(int dout, int q,
    fp Qr, fp Qi, fp Qj, fp Qk) {
  int br = dout >> 5, a = dout & 31;
  int bc = q >> 5, b = q & 31;
  int idx = a * 32 + b;
  fp Qm; float s;
  switch (br * 4 + bc) {
    case 0:  Qm = Qr; s =  1.f; break;
    case 1:  Qm = Qi; s = -1.f; break;
    case 2:  Qm = Qj; s = -1.f; break;
    case 3:  Qm = Qk; s = -1.f; break;
    case 4:  Qm = Qi; s =  1.f; break;
    case 5:  Qm = Qr; s =  1.f; break;
    case 6:  Qm = Qk; s = -1.f; break;
    case 7:  Qm = Qj; s =  1.f; break;
    case 8:  Qm = Qj; s =  1.f; break;
    case 9:  Qm = Qk; s =  1.f; break;
    case 10: Qm = Qr; s =  1.f; break;
    case 11: Qm = Qi; s = -1.f; break;
    case 12: Qm = Qk; s =  1.f; break;
    case 13: Qm = Qj; s = -1.f; break;
    default: Qm = (br*4+bc == 14) ? Qi : Qr; s = 1.f; break;
  }
  return s * Qm[idx];
}

// M0|M1|M2 (3 x 128x128) and c (128): fused linear maps of the quaternion fusion
__global__ void k_build_M(fp Pr_w, fp Pi_w, fp Pj_w, fp Pk_w,
                          fp Pr_b, fp Pi_b, fp Pj_b, fp Pk_b,
                          fp Qr, fp Qi, fp Qj, fp Qk, fp fusion_bias,
                          float* M, float* c) {
  int id = blockIdx.x * blockDim.x + threadIdx.x;
  if (id < 3 * 16384) {
    int m = id >> 14, rem = id & 16383, di = rem >> 7, dd = rem & 127;
    float acc = 0.f;
    for (int q = 0; q < 32; ++q)
      acc += Pr_w[(m * 128 + di) * 32 + q] * W_at(dd, q, Qr, Qi, Qj, Qk);
    fp Pm = (m == 0) ? Pi_w : (m == 1) ? Pj_w : Pk_w;
    int cb = 32 * (m + 1);
    for (int q = 0; q < 32; ++q)
      acc += Pm[di * 32 + q] * W_at(dd, cb + q, Qr, Qi, Qj, Qk);
    M[id] = acc;
  } else if (id < 3 * 16384 + 128) {
    int dd = id - 3 * 16384;
    float acc = fusion_bias ? fusion_bias[dd] : 0.f;
    for (int q = 0; q < 128; ++q) {
      fp Pb = (q < 32) ? Pr_b : (q < 64) ? Pi_b : (q < 96) ? Pj_b : Pk_b;
      acc += Pb[q & 31] * W_at(dd, q, Qr, Qi, Qj, Qk);
    }
    c[dd] = acc;
  }
}

// q,k,v (3 x E x D), batch-independent since v_he = relu(var_he_w) is
__global__ void k_qkv(fp var_he_w, fp Wq, fp bq, fp Wk, fp bk, fp Wv, fp bv,
                      float* qkv) {
  int id = blockIdx.x * blockDim.x + threadIdx.x;  // < 3*64*128
  int which = id >> 13; int rem = id & 8191; int e = rem >> 7, d = rem & 127;
  fp W = (which == 0) ? Wq : (which == 1) ? Wk : Wv;
  fp bb = (which == 0) ? bq : (which == 1) ? bk : bv;
  float acc = bb[d];
  for (int d2 = 0; d2 < 128; ++d2)
    acc += fmaxf(var_he_w[e * 128 + d2], 0.f) * W[d2 * 128 + d];
  qkv[id] = acc;
}

// scores0 (E x E), batch-independent
__global__ void k_scores(const float* qkv, float* sc) {
  int id = blockIdx.x * blockDim.x + threadIdx.x;  // < 4096
  int e = id >> 6, f = id & 63;
  const float* q = qkv;
  const float* k = qkv + E_ * D_;
  float acc = 0.f;
  for (int d = 0; d < 128; ++d) acc += q[e * 128 + d] * k[f * 128 + d];
  sc[id] = acc * 0.08838834764831845f;  // 1/sqrt(128)
}

// masked histogram of variable_indices -> cnt (B x E); aux diag = cnt/64
__global__ void k_hist(fp mask, const int* vidx, float* cnt) {
  __shared__ int c[64];
  int b = blockIdx.x;
  if (threadIdx.x < 64) c[threadIdx.x] = 0;
  __syncthreads();
  for (int n = threadIdx.x; n < N_; n += blockDim.x)
    if (mask[b * N_ + n] != 0.f)
      atomicAdd(&c[vidx[b * N_ + n] & 63], 1);
  __syncthreads();
  if (threadIdx.x < 64) cnt[b * 64 + threadIdx.x] = (float)c[threadIdx.x];
}

// per (b,e): diag-merged softmax row + v_he_att row (D)
__global__ void k_attn(const float* sc, const float* cnt, fp thr_p, fp mc_p,
                       const float* qkv, float* va) {
  __shared__ float attn_s[64];
  int bidx = blockIdx.x; int b = bidx >> 6, e = bidx & 63;
  int f = threadIdx.x;
  float s = sc[e * 64 + f];
  if (f == e) {
    float aux = cnt[b * 64 + e] * (1.f / 64.f);  // cnt / sqrt(N)
    float thr = thr_p ? thr_p[0] : 0.0f;
    float mc = mc_p ? mc_p[0] : 0.5f;
    if (aux != 0.f && s > thr) s = (1.f - mc) * s + mc * aux;
  }
  float m = s;
  for (int o = 32; o; o >>= 1) m = fmaxf(m, __shfl_xor(m, o));
  float ex = __expf(s - m);
  float sum = ex;
  for (int o = 32; o; o >>= 1) sum += __shfl_xor(sum, o);
  attn_s[f] = ex / sum;
  __syncthreads();
  const float* v = qkv + 2 * E_ * D_;
  float* out_row = va + (b * 64 + e) * 128;
  for (int d = f; d < 128; d += 64) {
    float acc = 0.f;
    for (int ff = 0; ff < 64; ++ff) acc += attn_s[ff] * v[ff * 128 + d];
    out_row[d] = acc;
  }
}

// VG[b,e,:] = v_he_att[b,e,:] @ M2
__global__ void k_vg(const float* va, const float* M2, float* VG) {
  int id = blockIdx.x * blockDim.x + threadIdx.x;  // < B*E*D
  int be = id >> 7, dd = id & 127;
  float acc = 0.f;
  for (int di = 0; di < 128; ++di) acc += va[be * 128 + di] * M2[di * 128 + dd];
  VG[id] = acc;
}

// TG[b,l,:] = sin(mark*W_temp + b_temp) @ M1
__global__ void k_tg(fp mark, fp W_temp, fp b_temp, const float* M1, float* TG) {
  __shared__ float t_row[128];
  int bl = blockIdx.x;  // b*L + l
  int d = threadIdx.x;
  float mk = mark[bl];
  t_row[d] = sinf(mk * W_temp[d] + b_temp[d]);
  __syncthreads();
  float acc = 0.f;
  for (int di = 0; di < 128; ++di) acc += t_row[di] * M1[di * 128 + d];
  TG[bl * 128 + d] = acc;
}

// out[b,n,:] = obs @ M0 + mask*(TG[b,t_idx] + VG[b,v_idx]) + c   (f32 output!)
__global__ __launch_bounds__(256) void k_main(
    fp x_L, fp x_y_mask, fp y_mask_L, const int* vidx, const int* tidx,
    fp W_obs, fp b_obs, const float* M0, const float* c,
    const float* TG, const float* VG, float* out) {
  __shared__ __hip_bfloat16 m0s[16384];
  __shared__ float cs[128];
  __shared__ float obs_s[2][128];
  int tid = threadIdx.x;
  for (int i = tid; i < 16384; i += 256) m0s[i] = __float2bfloat16(M0[i]);
  if (tid < 128) cs[tid] = c[tid];
  __syncthreads();
  int sub = tid >> 7, dd = tid & 127;
  for (int pass = 0; pass < 32; ++pass) {
    int node = blockIdx.x * 64 + pass * 2 + sub;
    float mask = x_y_mask[node];
    float xa = x_L[node];
    float xb = 1.f - mask + y_mask_L[node];
    float o = xa * W_obs[dd] + xb * W_obs[128 + dd] + b_obs[dd];
    o = fmaxf(o, 0.f) * mask;
    obs_s[sub][dd] = o;
    int b = node >> 12;
    int ti = tidx[node] & 255, vi = vidx[node] & 63;
    float acc = cs[dd] + mask * (TG[(b * 256 + ti) * 128 + dd] + VG[(b * 64 + vi) * 128 + dd]);
    __syncthreads();
#pragma unroll 16
    for (int di = 0; di < 128; ++di)
      acc += obs_s[sub][di] * __bfloat162float(m0s[di * 128 + dd]);
    out[node * 128 + dd] = acc;
    __syncthreads();
  }
}

extern "C" void kernel_launch(void* const* d_in, const int* in_sizes, int n_in,
                              void* d_out, int out_size, void* d_ws, size_t ws_size,
                              hipStream_t stream) {
  // Canonical 33-slot layout (setup_inputs dict order); slots 6/18/19 are
  // scalars, detected by size==1 (proven present: identity mapping).
  const void* P[33];
  {
    int p = 0;
    for (int i = 0; i < 33; ++i) {
      bool isopt = (i == 6 || i == 18 || i == 19);
      if (isopt) {
        if (p < n_in && in_sizes[p] == 1) P[i] = d_in[p++];
        else P[i] = nullptr;
      } else {
        P[i] = (p < n_in) ? d_in[p++] : nullptr;
      }
    }
  }
  fp x_L      = (fp)P[0];
  fp x_y_mask = (fp)P[1];
  fp y_mask_L = (fp)P[2];
  fp x_y_mark = (fp)P[3];
  const int* vidx = (const int*)P[4];
  const int* tidx = (const int*)P[5];
  fp W_obs = (fp)P[7];
  fp b_obs = (fp)P[8];
  fp W_temp = (fp)P[9];
  fp b_temp = (fp)P[10];
  fp var_he_w = (fp)P[11];
  fp Wq = (fp)P[12]; fp bq = (fp)P[13];
  fp Wk = (fp)P[14]; fp bk = (fp)P[15];
  fp Wv = (fp)P[16]; fp bv = (fp)P[17];
  fp thr = (fp)P[18]; fp mc = (fp)P[19];
  fp Pr_w = (fp)P[20]; fp Pr_b = (fp)P[21];
  fp Pi_w = (fp)P[22]; fp Pi_b = (fp)P[23];
  fp Pj_w = (fp)P[24]; fp Pj_b = (fp)P[25];
  fp Pk_w = (fp)P[26]; fp Pk_b = (fp)P[27];
  fp Qr = (fp)P[28]; fp Qi = (fp)P[29];
  fp Qj = (fp)P[30]; fp Qk = (fp)P[31];
  fp fusion_bias = (fp)P[32];

  float* ws  = (float*)d_ws;
  float* M   = ws;            // 3*16384
  float* c   = ws + 49152;    // 128
  float* qkv = ws + 49280;    // 3*8192
  float* sc  = ws + 73856;    // 4096
  float* cnt = ws + 77952;    // 512
  float* va  = ws + 78464;    // 65536
  float* VG  = ws + 144000;   // 65536
  float* TG  = ws + 209536;   // 262144  (end: 471680 floats ~ 1.8 MB)

  hipLaunchKernelGGL(k_build_M, dim3(385), dim3(128), 0, stream,
                     Pr_w, Pi_w, Pj_w, Pk_w, Pr_b, Pi_b, Pj_b, Pk_b,
                     Qr, Qi, Qj, Qk, fusion_bias, M, c);
  hipLaunchKernelGGL(k_qkv, dim3(96), dim3(256), 0, stream,
                     var_he_w, Wq, bq, Wk, bk, Wv, bv, qkv);
  hipLaunchKernelGGL(k_scores, dim3(16), dim3(256), 0, stream, qkv, sc);
  hipLaunchKernelGGL(k_hist, dim3(8), dim3(256), 0, stream, x_y_mask, vidx, cnt);
  hipLaunchKernelGGL(k_attn, dim3(512), dim3(64), 0, stream, sc, cnt, thr, mc, qkv, va);
  hipLaunchKernelGGL(k_vg, dim3(256), dim3(256), 0, stream, va, M + 32768, VG);
  hipLaunchKernelGGL(k_tg, dim3(2048), dim3(128), 0, stream,
                     x_y_mark, W_temp, b_temp, M + 16384, TG);
  hipLaunchKernelGGL(k_main, dim3(512), dim3(256), 0, stream,
                     x_L, x_y_mask, y_mask_L, vidx, tidx, W_obs, b_obs,
                     M, c, TG, VG, (float*)d_out);
}

// Round 6
// 88.172 us; speedup vs baseline: 2.0236x; 2.0236x over previous
//
#include <hip/hip_runtime.h>
#include <hip/hip_bf16.h>

// B=8, N=4096, L=256, E=64, D=128, Q4=32
#define B_ 8
#define N_ 4096
#define L_ 256
#define E_ 64
#define D_ 128

typedef const float* fp;
typedef __attribute__((ext_vector_type(8))) short short8;
typedef __attribute__((ext_vector_type(4))) float f32x4;

__device__ __forceinline__ float W_at(int dout, int q,
    fp Qr, fp Qi, fp Qj, fp Qk) {
  int br = dout >> 5, a = dout & 31;
  int bc = q >> 5, b = q & 31;
  int idx = a * 32 + b;
  fp Qm; float s;
  switch (br * 4 + bc) {
    case 0:  Qm = Qr; s =  1.f; break;
    case 1:  Qm = Qi; s = -1.f; break;
    case 2:  Qm = Qj; s = -1.f; break;
    case 3:  Qm = Qk; s = -1.f; break;
    case 4:  Qm = Qi; s =  1.f; break;
    case 5:  Qm = Qr; s =  1.f; break;
    case 6:  Qm = Qk; s = -1.f; break;
    case 7:  Qm = Qj; s =  1.f; break;
    case 8:  Qm = Qj; s =  1.f; break;
    case 9:  Qm = Qk; s =  1.f; break;
    case 10: Qm = Qr; s =  1.f; break;
    case 11: Qm = Qi; s = -1.f; break;
    case 12: Qm = Qk; s =  1.f; break;
    case 13: Qm = Qj; s = -1.f; break;
    default: Qm = (br*4+bc == 14) ? Qi : Qr; s = 1.f; break;
  }
  return s * Qm[idx];
}

__device__ __forceinline__ short f2bf(float x) {
  __hip_bfloat16 h = __float2bfloat16(x);
  return __builtin_bit_cast(short, h);
}

// K1: fused setup. blocks 0..192: M0T/M1/M2 + c. 193..288: qkv. 289..296: hist.
__global__ __launch_bounds__(256) void k_setup(
    fp Pr_w, fp Pi_w, fp Pj_w, fp Pk_w,
    fp Pr_b, fp Pi_b, fp Pj_b, fp Pk_b,
    fp Qr, fp Qi, fp Qj, fp Qk, fp fusion_bias,
    fp var_he_w, fp Wq, fp bq, fp Wk, fp bk, fp Wv, fp bv,
    fp xmask, const int* vidx,
    float* ws) {
  __shared__ int hc[64];
  int bid = blockIdx.x, tid = threadIdx.x;
  float* M = ws;            // M0T | M1 | M2
  float* c = ws + 49152;
  float* qkv = ws + 49280;
  float* cnt = ws + 73856;
  if (bid < 193) {
    int id = bid * 256 + tid;
    if (id < 49152) {
      int m = id >> 14, rem = id & 16383, di = rem >> 7, dd = rem & 127;
      float acc = 0.f;
      for (int q = 0; q < 32; ++q)
        acc += Pr_w[(m * 128 + di) * 32 + q] * W_at(dd, q, Qr, Qi, Qj, Qk);
      fp Pm = (m == 0) ? Pi_w : (m == 1) ? Pj_w : Pk_w;
      int cb = 32 * (m + 1);
      for (int q = 0; q < 32; ++q)
        acc += Pm[di * 32 + q] * W_at(dd, cb + q, Qr, Qi, Qj, Qk);
      if (m == 0) M[dd * 128 + di] = acc;        // M0 transposed
      else M[m * 16384 + di * 128 + dd] = acc;   // M1, M2 row-major
    } else if (id < 49280) {
      int dd = id - 49152;
      float acc = fusion_bias ? fusion_bias[dd] : 0.f;
      for (int q = 0; q < 128; ++q) {
        fp Pb = (q < 32) ? Pr_b : (q < 64) ? Pi_b : (q < 96) ? Pj_b : Pk_b;
        acc += Pb[q & 31] * W_at(dd, q, Qr, Qi, Qj, Qk);
      }
      c[dd] = acc;
    }
  } else if (bid < 289) {
    int id = (bid - 193) * 256 + tid;  // < 24576
    int which = id >> 13, rem = id & 8191, e = rem >> 7, d = rem & 127;
    fp W = (which == 0) ? Wq : (which == 1) ? Wk : Wv;
    fp bb = (which == 0) ? bq : (which == 1) ? bk : bv;
    float acc = bb[d];
    for (int d2 = 0; d2 < 128; ++d2)
      acc += fmaxf(var_he_w[e * 128 + d2], 0.f) * W[d2 * 128 + d];
    qkv[id] = acc;
  } else {
    int b = bid - 289;  // < 8
    if (tid < 64) hc[tid] = 0;
    __syncthreads();
    for (int n = tid; n < N_; n += 256)
      if (xmask[b * N_ + n] != 0.f)
        atomicAdd(&hc[vidx[b * N_ + n] & 63], 1);
    __syncthreads();
    if (tid < 64) cnt[b * 64 + tid] = (float)hc[tid];
  }
}

// K2: blocks 0..511: per-(b,e) scores->softmax->va->VG row.
//     blocks 512..2559: TG rows.
__global__ __launch_bounds__(128) void k_mid(
    fp thr_p, fp mc_p, fp mark, fp W_temp, fp b_temp,
    float* ws) {
  __shared__ float buf[128];
  __shared__ float attn_s[64];
  const float* M1 = ws + 16384;
  const float* M2 = ws + 32768;
  const float* qkv = ws + 49280;
  const float* cnt = ws + 73856;
  float* VG = ws + 74368;
  float* TG = ws + 139904;
  int bid = blockIdx.x, t = threadIdx.x;
  if (bid < 512) {
    int b = bid >> 6, e = bid & 63;
    const float* q = qkv;
    const float* k = qkv + 8192;
    const float* v = qkv + 16384;
    int f = t & 63, h = t >> 6;
    float part = 0.f;
    for (int d = h * 64; d < h * 64 + 64; ++d)
      part += q[e * 128 + d] * k[f * 128 + d];
    buf[t] = part;
    __syncthreads();
    if (t < 64) {
      float s = (buf[t] + buf[t + 64]) * 0.08838834764831845f;
      if (t == e) {
        float aux = cnt[b * 64 + e] * (1.f / 64.f);
        float thv = thr_p ? thr_p[0] : 0.f;
        float mc = mc_p ? mc_p[0] : 0.5f;
        if (aux != 0.f && s > thv) s = (1.f - mc) * s + mc * aux;
      }
      float m = s;
      for (int o = 32; o; o >>= 1) m = fmaxf(m, __shfl_xor(m, o));
      float ex = __expf(s - m);
      float sum = ex;
      for (int o = 32; o; o >>= 1) sum += __shfl_xor(sum, o);
      attn_s[t] = ex / sum;
    }
    __syncthreads();
    float va = 0.f;
    for (int ff = 0; ff < 64; ++ff) va += attn_s[ff] * v[ff * 128 + t];
    __syncthreads();
    buf[t] = va;
    __syncthreads();
    float acc = 0.f;
    for (int di = 0; di < 128; ++di) acc += buf[di] * M2[di * 128 + t];
    VG[(b * 64 + e) * 128 + t] = acc;
  } else {
    int bl = bid - 512;  // b*L + l
    buf[t] = sinf(mark[bl] * W_temp[t] + b_temp[t]);
    __syncthreads();
    float acc = 0.f;
    for (int di = 0; di < 128; ++di) acc += buf[di] * M1[di * 128 + t];
    TG[bl * 128 + t] = acc;
  }
}

// K3: MFMA main. Block = 64 nodes, 4 waves x 16 nodes. Wave computes
// obs A-frags in registers, M0 B-frags from fragment-ordered LDS, then
// 32 mfma_f32_16x16x32_bf16, epilogue adds c + mask*(TG+VG) gathers.
__global__ __launch_bounds__(256, 2) void k_mainf(
    fp x_L, fp x_y_mask, fp y_mask_L, const int* vidx, const int* tidx,
    fp W_obs, fp b_obs, const float* ws, float* out) {
  __shared__ short m0f[16384];   // fragment-ordered M0 (bf16 bits)
  __shared__ float cs[128];
  const float* M0T = ws;         // [dd][di]
  const float* c = ws + 49152;
  const float* VG = ws + 74368;
  const float* TG = ws + 139904;
  int tid = threadIdx.x;
  // stage M0 -> fragment order: elem (fn,ft,lane,j):
  //   k = ft*32 + (lane>>4)*8 + j ; dd = fn*16 + (lane&15)
#pragma unroll
  for (int i = 0; i < 64; ++i) {
    int lid = tid + i * 256;
    int j = lid & 7, lane = (lid >> 3) & 63, ft = (lid >> 9) & 3, fn = lid >> 11;
    int k = ft * 32 + ((lane >> 4) << 3) + j;
    int dd = (fn << 4) + (lane & 15);
    m0f[lid] = f2bf(M0T[dd * 128 + k]);
  }
  if (tid < 128) cs[tid] = c[tid];
  __syncthreads();

  int w = tid >> 6, l = tid & 63;
  int nb = blockIdx.x * 64 + w * 16;
  int b = blockIdx.x >> 6;

  // B-frags from LDS (consecutive-lane b128 reads)
  const short8* fr = (const short8*)m0f;
  short8 bf[8][4];
#pragma unroll
  for (int fn = 0; fn < 8; ++fn)
#pragma unroll
    for (int ft = 0; ft < 4; ++ft)
      bf[fn][ft] = fr[(fn * 4 + ft) * 64 + l];

  // A-frags: obs for node nb+(l&15), k-cols ft*32+(l>>4)*8+j
  int nodeA = nb + (l & 15);
  float mask = x_y_mask[nodeA];
  float xa = x_L[nodeA];
  float xb = 1.f - mask + y_mask_L[nodeA];
  short8 af[4];
#pragma unroll
  for (int ft = 0; ft < 4; ++ft) {
#pragma unroll
    for (int j = 0; j < 8; ++j) {
      int col = ft * 32 + ((l >> 4) << 3) + j;
      float o = fmaxf(xa * W_obs[col] + xb * W_obs[128 + col] + b_obs[col], 0.f) * mask;
      af[ft][j] = f2bf(o);
    }
  }

  f32x4 acc[8];
#pragma unroll
  for (int fn = 0; fn < 8; ++fn) acc[fn] = (f32x4)(0.f);
#pragma unroll
  for (int fn = 0; fn < 8; ++fn)
#pragma unroll
    for (int ft = 0; ft < 4; ++ft)
      acc[fn] = __builtin_amdgcn_mfma_f32_16x16x32_bf16(af[ft], bf[fn][ft], acc[fn], 0, 0, 0);

  // epilogue: C layout col=lane&15, row=(lane>>4)*4+reg
  int colbase = l & 15;
#pragma unroll
  for (int rg = 0; rg < 4; ++rg) {
    int node = nb + ((l >> 4) << 2) + rg;
    float m2 = x_y_mask[node];
    int ti = tidx[node] & 255, vi = vidx[node] & 63;
    const float* tgr = TG + (b * 256 + ti) * 128;
    const float* vgr = VG + (b * 64 + vi) * 128;
    float* orow = out + node * 128;
#pragma unroll
    for (int fn = 0; fn < 8; ++fn) {
      int col = fn * 16 + colbase;
      orow[col] = acc[fn][rg] + cs[col] + m2 * (tgr[col] + vgr[col]);
    }
  }
}

extern "C" void kernel_launch(void* const* d_in, const int* in_sizes, int n_in,
                              void* d_out, int out_size, void* d_ws, size_t ws_size,
                              hipStream_t stream) {
  // Canonical 33-slot layout (setup_inputs dict order); slots 6/18/19 are
  // scalars, detected by size==1 (proven present: identity mapping).
  const void* P[33];
  {
    int p = 0;
    for (int i = 0; i < 33; ++i) {
      bool isopt = (i == 6 || i == 18 || i == 19);
      if (isopt) {
        if (p < n_in && in_sizes[p] == 1) P[i] = d_in[p++];
        else P[i] = nullptr;
      } else {
        P[i] = (p < n_in) ? d_in[p++] : nullptr;
      }
    }
  }
  fp x_L      = (fp)P[0];
  fp x_y_mask = (fp)P[1];
  fp y_mask_L = (fp)P[2];
  fp x_y_mark = (fp)P[3];
  const int* vidx = (const int*)P[4];
  const int* tidx = (const int*)P[5];
  fp W_obs = (fp)P[7];
  fp b_obs = (fp)P[8];
  fp W_temp = (fp)P[9];
  fp b_temp = (fp)P[10];
  fp var_he_w = (fp)P[11];
  fp Wq = (fp)P[12]; fp bq = (fp)P[13];
  fp Wk = (fp)P[14]; fp bk = (fp)P[15];
  fp Wv = (fp)P[16]; fp bv = (fp)P[17];
  fp thr = (fp)P[18]; fp mc = (fp)P[19];
  fp Pr_w = (fp)P[20]; fp Pr_b = (fp)P[21];
  fp Pi_w = (fp)P[22]; fp Pi_b = (fp)P[23];
  fp Pj_w = (fp)P[24]; fp Pj_b = (fp)P[25];
  fp Pk_w = (fp)P[26]; fp Pk_b = (fp)P[27];
  fp Qr = (fp)P[28]; fp Qi = (fp)P[29];
  fp Qj = (fp)P[30]; fp Qk = (fp)P[31];
  fp fusion_bias = (fp)P[32];

  float* ws = (float*)d_ws;
  // ws: M0T[16384] | M1[16384] | M2[16384] | c[128] | qkv[24576] |
  //     cnt[512] | VG[65536] | TG[262144]   (end 402048 floats = 1.6 MB)

  hipLaunchKernelGGL(k_setup, dim3(297), dim3(256), 0, stream,
                     Pr_w, Pi_w, Pj_w, Pk_w, Pr_b, Pi_b, Pj_b, Pk_b,
                     Qr, Qi, Qj, Qk, fusion_bias,
                     var_he_w, Wq, bq, Wk, bk, Wv, bv,
                     x_y_mask, vidx, ws);
  hipLaunchKernelGGL(k_mid, dim3(2560), dim3(128), 0, stream,
                     thr, mc, x_y_mark, W_temp, b_temp, ws);
  hipLaunchKernelGGL(k_mainf, dim3(512), dim3(256), 0, stream,
                     x_L, x_y_mask, y_mask_L, vidx, tidx, W_obs, b_obs,
                     ws, (float*)d_out);
}

// Round 7
// 46.314 us; speedup vs baseline: 3.8524x; 1.9038x over previous
//
#include <hip/hip_runtime.h>
#include <hip/hip_bf16.h>

// B=8, N=4096, L=256, E=64, D=128, Q4=32
#define B_ 8
#define N_ 4096
#define L_ 256
#define E_ 64
#define D_ 128

typedef const float* fp;
typedef __attribute__((ext_vector_type(8))) short short8;
typedef __attribute__((ext_vector_type(4))) float f32x4;

__device__ __forceinline__ short f2bf(float x) {
  __hip_bfloat16 h = __float2bfloat16(x);
  return __builtin_bit_cast(short, h);
}

// quaternion block tables: W[dout,q] block (br,bc) = sgn * Qsel[a*32+b]
__device__ __constant__ int   selT[16] = {0,1,2,3, 1,0,3,2, 2,3,0,1, 3,2,1,0};
__device__ __constant__ float sgnT[16] = {1.f,-1.f,-1.f,-1.f, 1.f,1.f,-1.f,1.f,
                                          1.f,1.f,1.f,-1.f, 1.f,-1.f,1.f,1.f};

// K1: blocks 0..95: M build (LDS-staged Q). 96..191: qkv. 192..199: hist.
__global__ __launch_bounds__(256) void k_setup(
    fp Pr_w, fp Pi_w, fp Pj_w, fp Pk_w,
    fp Pr_b, fp Pi_b, fp Pj_b, fp Pk_b,
    fp Qr, fp Qi, fp Qj, fp Qk, fp fusion_bias,
    fp var_he_w, fp Wq, fp bq, fp Wk, fp bk, fp Wv, fp bv,
    fp xmask, const int* vidx,
    float* ws) {
  int bid = blockIdx.x, tid = threadIdx.x;
  float* M = ws;            // M0T | M1 | M2
  float* c = ws + 49152;
  float* qkv = ws + 49280;
  float* cnt = ws + 73856;
  if (bid < 96) {
    __shared__ float qlds[4][32][33];   // +1 pad: a-stride 33 kills conflicts
    {
      fp Qsrc[4] = {Qr, Qi, Qj, Qk};
      for (int lid = tid; lid < 4096; lid += 256) {
        int mat = lid >> 10, el = lid & 1023;
        qlds[mat][el >> 5][el & 31] = Qsrc[mat][el];
      }
    }
    __syncthreads();
    int m = bid >> 5, di0 = (bid & 31) * 4;
    int sub = tid >> 7, dd = tid & 127;
    int br = dd >> 5, a = dd & 31;
    const float* w0 = qlds[br][a];                 // bc=0 row, sign +1
    int t1 = br * 4 + m + 1;
    const float* w1 = qlds[selT[t1]][a];
    float s1 = sgnT[t1];
    fp Pm = (m == 0) ? Pi_w : (m == 1) ? Pj_w : Pk_w;
#pragma unroll
    for (int ii = 0; ii < 2; ++ii) {
      int di = di0 + ii * 2 + sub;
      const float* pr = Pr_w + (m * 128 + di) * 32;
      const float* pm = Pm + di * 32;
      float acc = 0.f;
#pragma unroll
      for (int q = 0; q < 32; ++q)
        acc += pr[q] * w0[q] + s1 * pm[q] * w1[q];
      if (m == 0) M[dd * 128 + di] = acc;          // M0 transposed
      else M[m * 16384 + di * 128 + dd] = acc;     // M1, M2 row-major
    }
    if (bid == 0 && tid < 128) {                   // c vector
      float acc = fusion_bias ? fusion_bias[tid] : 0.f;
#pragma unroll
      for (int bc = 0; bc < 4; ++bc) {
        fp Pb = (bc == 0) ? Pr_b : (bc == 1) ? Pi_b : (bc == 2) ? Pj_b : Pk_b;
        int t = br * 4 + bc;
        const float* wr = qlds[selT[t]][a];
        float sg = sgnT[t];
        float part = 0.f;
#pragma unroll
        for (int q = 0; q < 32; ++q) part += Pb[q] * wr[q];
        acc += sg * part;
      }
      c[tid] = acc;
    }
  } else if (bid < 192) {
    int id = (bid - 96) * 256 + tid;  // < 24576
    int which = id >> 13, rem = id & 8191, e = rem >> 7, d = rem & 127;
    fp W = (which == 0) ? Wq : (which == 1) ? Wk : Wv;
    fp bb = (which == 0) ? bq : (which == 1) ? bk : bv;
    float acc = bb[d];
    for (int d2 = 0; d2 < 128; ++d2)
      acc += fmaxf(var_he_w[e * 128 + d2], 0.f) * W[d2 * 128 + d];
    qkv[id] = acc;
  } else {
    __shared__ int hc[64];
    int b = bid - 192;  // < 8
    if (tid < 64) hc[tid] = 0;
    __syncthreads();
    for (int n = tid; n < N_; n += 256)
      if (xmask[b * N_ + n] != 0.f)
        atomicAdd(&hc[vidx[b * N_ + n] & 63], 1);
    __syncthreads();
    if (tid < 64) cnt[b * 64 + tid] = (float)hc[tid];
  }
}

// K2: blocks 0..511: per-(b,e) scores->softmax->va->VG row.
//     blocks 512..2559: TG rows.
__global__ __launch_bounds__(128) void k_mid(
    fp thr_p, fp mc_p, fp mark, fp W_temp, fp b_temp,
    float* ws) {
  __shared__ float buf[128];
  __shared__ float attn_s[64];
  const float* M1 = ws + 16384;
  const float* M2 = ws + 32768;
  const float* qkv = ws + 49280;
  const float* cnt = ws + 73856;
  float* VG = ws + 74368;
  float* TG = ws + 139904;
  int bid = blockIdx.x, t = threadIdx.x;
  if (bid < 512) {
    int b = bid >> 6, e = bid & 63;
    const float* q = qkv;
    const float* k = qkv + 8192;
    const float* v = qkv + 16384;
    int f = t & 63, h = t >> 6;
    float part = 0.f;
    for (int d = h * 64; d < h * 64 + 64; ++d)
      part += q[e * 128 + d] * k[f * 128 + d];
    buf[t] = part;
    __syncthreads();
    if (t < 64) {
      float s = (buf[t] + buf[t + 64]) * 0.08838834764831845f;
      if (t == e) {
        float aux = cnt[b * 64 + e] * (1.f / 64.f);
        float thv = thr_p ? thr_p[0] : 0.f;
        float mc = mc_p ? mc_p[0] : 0.5f;
        if (aux != 0.f && s > thv) s = (1.f - mc) * s + mc * aux;
      }
      float m = s;
      for (int o = 32; o; o >>= 1) m = fmaxf(m, __shfl_xor(m, o));
      float ex = __expf(s - m);
      float sum = ex;
      for (int o = 32; o; o >>= 1) sum += __shfl_xor(sum, o);
      attn_s[t] = ex / sum;
    }
    __syncthreads();
    float va = 0.f;
    for (int ff = 0; ff < 64; ++ff) va += attn_s[ff] * v[ff * 128 + t];
    __syncthreads();
    buf[t] = va;
    __syncthreads();
    float acc = 0.f;
    for (int di = 0; di < 128; ++di) acc += buf[di] * M2[di * 128 + t];
    VG[(b * 64 + e) * 128 + t] = acc;
  } else {
    int bl = bid - 512;  // b*L + l
    buf[t] = sinf(mark[bl] * W_temp[t] + b_temp[t]);
    __syncthreads();
    float acc = 0.f;
    for (int di = 0; di < 128; ++di) acc += buf[di] * M1[di * 128 + t];
    TG[bl * 128 + t] = acc;
  }
}

// K3: MFMA main. Block = 64 nodes, 4 waves x 16 nodes.
__global__ __launch_bounds__(256, 2) void k_mainf(
    fp x_L, fp x_y_mask, fp y_mask_L, const int* vidx, const int* tidx,
    fp W_obs, fp b_obs, const float* ws, float* out) {
  __shared__ short m0f[16384];   // fragment-ordered M0 (bf16 bits)
  __shared__ float cs[128];
  const float* M0T = ws;         // [dd][di]
  const float* c = ws + 49152;
  const float* VG = ws + 74368;
  const float* TG = ws + 139904;
  int tid = threadIdx.x;
#pragma unroll
  for (int i = 0; i < 64; ++i) {
    int lid = tid + i * 256;
    int j = lid & 7, lane = (lid >> 3) & 63, ft = (lid >> 9) & 3, fn = lid >> 11;
    int k = ft * 32 + ((lane >> 4) << 3) + j;
    int dd = (fn << 4) + (lane & 15);
    m0f[lid] = f2bf(M0T[dd * 128 + k]);
  }
  if (tid < 128) cs[tid] = c[tid];
  __syncthreads();

  int w = tid >> 6, l = tid & 63;
  int nb = blockIdx.x * 64 + w * 16;
  int b = blockIdx.x >> 6;

  const short8* fr = (const short8*)m0f;
  short8 bf[8][4];
#pragma unroll
  for (int fn = 0; fn < 8; ++fn)
#pragma unroll
    for (int ft = 0; ft < 4; ++ft)
      bf[fn][ft] = fr[(fn * 4 + ft) * 64 + l];

  int nodeA = nb + (l & 15);
  float mask = x_y_mask[nodeA];
  float xa = x_L[nodeA];
  float xb = 1.f - mask + y_mask_L[nodeA];
  short8 af[4];
#pragma unroll
  for (int ft = 0; ft < 4; ++ft) {
#pragma unroll
    for (int j = 0; j < 8; ++j) {
      int col = ft * 32 + ((l >> 4) << 3) + j;
      float o = fmaxf(xa * W_obs[col] + xb * W_obs[128 + col] + b_obs[col], 0.f) * mask;
      af[ft][j] = f2bf(o);
    }
  }

  f32x4 acc[8];
#pragma unroll
  for (int fn = 0; fn < 8; ++fn) acc[fn] = (f32x4)(0.f);
#pragma unroll
  for (int fn = 0; fn < 8; ++fn)
#pragma unroll
    for (int ft = 0; ft < 4; ++ft)
      acc[fn] = __builtin_amdgcn_mfma_f32_16x16x32_bf16(af[ft], bf[fn][ft], acc[fn], 0, 0, 0);

  int colbase = l & 15;
#pragma unroll
  for (int rg = 0; rg < 4; ++rg) {
    int node = nb + ((l >> 4) << 2) + rg;
    float m2 = x_y_mask[node];
    int ti = tidx[node] & 255, vi = vidx[node] & 63;
    const float* tgr = TG + (b * 256 + ti) * 128;
    const float* vgr = VG + (b * 64 + vi) * 128;
    float* orow = out + node * 128;
#pragma unroll
    for (int fn = 0; fn < 8; ++fn) {
      int col = fn * 16 + colbase;
      orow[col] = acc[fn][rg] + cs[col] + m2 * (tgr[col] + vgr[col]);
    }
  }
}

extern "C" void kernel_launch(void* const* d_in, const int* in_sizes, int n_in,
                              void* d_out, int out_size, void* d_ws, size_t ws_size,
                              hipStream_t stream) {
  const void* P[33];
  {
    int p = 0;
    for (int i = 0; i < 33; ++i) {
      bool isopt = (i == 6 || i == 18 || i == 19);
      if (isopt) {
        if (p < n_in && in_sizes[p] == 1) P[i] = d_in[p++];
        else P[i] = nullptr;
      } else {
        P[i] = (p < n_in) ? d_in[p++] : nullptr;
      }
    }
  }
  fp x_L      = (fp)P[0];
  fp x_y_mask = (fp)P[1];
  fp y_mask_L = (fp)P[2];
  fp x_y_mark = (fp)P[3];
  const int* vidx = (const int*)P[4];
  const int* tidx = (const int*)P[5];
  fp W_obs = (fp)P[7];
  fp b_obs = (fp)P[8];
  fp W_temp = (fp)P[9];
  fp b_temp = (fp)P[10];
  fp var_he_w = (fp)P[11];
  fp Wq = (fp)P[12]; fp bq = (fp)P[13];
  fp Wk = (fp)P[14]; fp bk = (fp)P[15];
  fp Wv = (fp)P[16]; fp bv = (fp)P[17];
  fp thr = (fp)P[18]; fp mc = (fp)P[19];
  fp Pr_w = (fp)P[20]; fp Pr_b = (fp)P[21];
  fp Pi_w = (fp)P[22]; fp Pi_b = (fp)P[23];
  fp Pj_w = (fp)P[24]; fp Pj_b = (fp)P[25];
  fp Pk_w = (fp)P[26]; fp Pk_b = (fp)P[27];
  fp Qr = (fp)P[28]; fp Qi = (fp)P[29];
  fp Qj = (fp)P[30]; fp Qk = (fp)P[31];
  fp fusion_bias = (fp)P[32];

  float* ws = (float*)d_ws;
  // ws: M0T[16384] | M1[16384] | M2[16384] | c[128] | qkv[24576] |
  //     cnt[512] | VG[65536] | TG[262144]

  hipLaunchKernelGGL(k_setup, dim3(200), dim3(256), 0, stream,
                     Pr_w, Pi_w, Pj_w, Pk_w, Pr_b, Pi_b, Pj_b, Pk_b,
                     Qr, Qi, Qj, Qk, fusion_bias,
                     var_he_w, Wq, bq, Wk, bk, Wv, bv,
                     x_y_mask, vidx, ws);
  hipLaunchKernelGGL(k_mid, dim3(2560), dim3(128), 0, stream,
                     thr, mc, x_y_mark, W_temp, b_temp, ws);
  hipLaunchKernelGGL(k_mainf, dim3(512), dim3(256), 0, stream,
                     x_L, x_y_mask, y_mask_L, vidx, tidx, W_obs, b_obs,
                     ws, (float*)d_out);
}

// Round 8
// 42.866 us; speedup vs baseline: 4.1624x; 1.0804x over previous
//
#include <hip/hip_runtime.h>
#include <hip/hip_bf16.h>

// B=8, N=4096, L=256, E=64, D=128, Q4=32
#define B_ 8
#define N_ 4096
#define L_ 256
#define E_ 64
#define D_ 128

typedef const float* fp;
typedef __attribute__((ext_vector_type(8))) short short8;
typedef __attribute__((ext_vector_type(4))) float f32x4;

__device__ __forceinline__ short f2bf(float x) {
  __hip_bfloat16 h = __float2bfloat16(x);
  return __builtin_bit_cast(short, h);
}

// quaternion block tables: W[dout,q] block (br,bc) = sgn * Qsel[a*32+b]
__device__ __constant__ int   selT[16] = {0,1,2,3, 1,0,3,2, 2,3,0,1, 3,2,1,0};
__device__ __constant__ float sgnT[16] = {1.f,-1.f,-1.f,-1.f, 1.f,1.f,-1.f,1.f,
                                          1.f,1.f,1.f,-1.f, 1.f,-1.f,1.f,1.f};

// ws layout (floats):
//   [0,8192)        m0frag: 16384 ushorts, bf16 M0 in MFMA B-fragment order
//   [16384,32768)   M1 row-major
//   [32768,49152)   M2 row-major
//   [49152,49280)   c
//   [49280,73856)   qkv
//   [73856,74368)   cnt
//   [74368,139904)  VG
//   [139904,402048) TG

// K1: blocks 0..95: M build (LDS-staged Q). 96..191: qkv. 192..199: hist.
__global__ __launch_bounds__(256) void k_setup(
    fp Pr_w, fp Pi_w, fp Pj_w, fp Pk_w,
    fp Pr_b, fp Pi_b, fp Pj_b, fp Pk_b,
    fp Qr, fp Qi, fp Qj, fp Qk, fp fusion_bias,
    fp var_he_w, fp Wq, fp bq, fp Wk, fp bk, fp Wv, fp bv,
    fp xmask, const int* vidx,
    float* ws) {
  int bid = blockIdx.x, tid = threadIdx.x;
  float* M = ws;
  unsigned short* m0frag = (unsigned short*)ws;
  float* c = ws + 49152;
  float* qkv = ws + 49280;
  float* cnt = ws + 73856;
  if (bid < 96) {
    __shared__ float qlds[4][32][33];   // +1 pad: a-stride 33 kills conflicts
    {
      fp Qsrc[4] = {Qr, Qi, Qj, Qk};
      for (int lid = tid; lid < 4096; lid += 256) {
        int mat = lid >> 10, el = lid & 1023;
        qlds[mat][el >> 5][el & 31] = Qsrc[mat][el];
      }
    }
    __syncthreads();
    int m = bid >> 5, di0 = (bid & 31) * 4;
    int sub = tid >> 7, dd = tid & 127;
    int br = dd >> 5, a = dd & 31;
    const float* w0 = qlds[br][a];                 // bc=0 row, sign +1
    int t1 = br * 4 + m + 1;
    const float* w1 = qlds[selT[t1]][a];
    float s1 = sgnT[t1];
    fp Pm = (m == 0) ? Pi_w : (m == 1) ? Pj_w : Pk_w;
#pragma unroll
    for (int ii = 0; ii < 2; ++ii) {
      int di = di0 + ii * 2 + sub;
      const float* pr = Pr_w + (m * 128 + di) * 32;
      const float* pm = Pm + di * 32;
      float acc = 0.f;
#pragma unroll
      for (int q = 0; q < 32; ++q)
        acc += pr[q] * w0[q] + s1 * pm[q] * w1[q];
      if (m == 0) {
        // bf16 fragment order: frag f=fn*4+ft, lane l=hi*16+(dd&15), elem j
        int fn = dd >> 4, ft = di >> 5, hi = (di >> 3) & 3, j = di & 7;
        int l = hi * 16 + (dd & 15);
        m0frag[((fn * 4 + ft) * 64 + l) * 8 + j] = (unsigned short)f2bf(acc);
      } else {
        M[m * 16384 + di * 128 + dd] = acc;       // M1, M2 row-major
      }
    }
    if (bid == 0 && tid < 128) {                   // c vector
      float acc = fusion_bias ? fusion_bias[tid] : 0.f;
#pragma unroll
      for (int bc = 0; bc < 4; ++bc) {
        fp Pb = (bc == 0) ? Pr_b : (bc == 1) ? Pi_b : (bc == 2) ? Pj_b : Pk_b;
        int t = br * 4 + bc;
        const float* wr = qlds[selT[t]][a];
        float sg = sgnT[t];
        float part = 0.f;
#pragma unroll
        for (int q = 0; q < 32; ++q) part += Pb[q] * wr[q];
        acc += sg * part;
      }
      c[tid] = acc;
    }
  } else if (bid < 192) {
    int id = (bid - 96) * 256 + tid;  // < 24576
    int which = id >> 13, rem = id & 8191, e = rem >> 7, d = rem & 127;
    fp W = (which == 0) ? Wq : (which == 1) ? Wk : Wv;
    fp bb = (which == 0) ? bq : (which == 1) ? bk : bv;
    float acc = bb[d];
    for (int d2 = 0; d2 < 128; ++d2)
      acc += fmaxf(var_he_w[e * 128 + d2], 0.f) * W[d2 * 128 + d];
    qkv[id] = acc;
  } else {
    __shared__ int hc[64];
    int b = bid - 192;  // < 8
    if (tid < 64) hc[tid] = 0;
    __syncthreads();
    for (int n = tid; n < N_; n += 256)
      if (xmask[b * N_ + n] != 0.f)
        atomicAdd(&hc[vidx[b * N_ + n] & 63], 1);
    __syncthreads();
    if (tid < 64) cnt[b * 64 + tid] = (float)hc[tid];
  }
}

// K2: blocks 0..511: per-(b,e) scores->softmax->va->VG row.
//     blocks 512..1023: TG, 4 rows per block (M1 loads shared x4).
__global__ __launch_bounds__(128) void k_mid(
    fp thr_p, fp mc_p, fp mark, fp W_temp, fp b_temp,
    float* ws) {
  const float* M1 = ws + 16384;
  const float* M2 = ws + 32768;
  const float* qkv = ws + 49280;
  const float* cnt = ws + 73856;
  float* VG = ws + 74368;
  float* TG = ws + 139904;
  int bid = blockIdx.x, t = threadIdx.x;
  if (bid < 512) {
    __shared__ float buf[128];
    __shared__ float attn_s[64];
    int b = bid >> 6, e = bid & 63;
    const float* q = qkv;
    const float* k = qkv + 8192;
    const float* v = qkv + 16384;
    int f = t & 63, h = t >> 6;
    float part = 0.f;
    for (int d = h * 64; d < h * 64 + 64; ++d)
      part += q[e * 128 + d] * k[f * 128 + d];
    buf[t] = part;
    __syncthreads();
    if (t < 64) {
      float s = (buf[t] + buf[t + 64]) * 0.08838834764831845f;
      if (t == e) {
        float aux = cnt[b * 64 + e] * (1.f / 64.f);
        float thv = thr_p ? thr_p[0] : 0.f;
        float mc = mc_p ? mc_p[0] : 0.5f;
        if (aux != 0.f && s > thv) s = (1.f - mc) * s + mc * aux;
      }
      float m = s;
      for (int o = 32; o; o >>= 1) m = fmaxf(m, __shfl_xor(m, o));
      float ex = __expf(s - m);
      float sum = ex;
      for (int o = 32; o; o >>= 1) sum += __shfl_xor(sum, o);
      attn_s[t] = ex / sum;
    }
    __syncthreads();
    float va = 0.f;
    for (int ff = 0; ff < 64; ++ff) va += attn_s[ff] * v[ff * 128 + t];
    __syncthreads();
    buf[t] = va;
    __syncthreads();
    float acc = 0.f;
    for (int di = 0; di < 128; ++di) acc += buf[di] * M2[di * 128 + t];
    VG[(b * 64 + e) * 128 + t] = acc;
  } else {
    __shared__ float tb[4][128];
    int r0 = (bid - 512) * 4;  // flattened b*L+l row base
#pragma unroll
    for (int r = 0; r < 4; ++r)
      tb[r][t] = sinf(mark[r0 + r] * W_temp[t] + b_temp[t]);
    __syncthreads();
    float a0 = 0.f, a1 = 0.f, a2 = 0.f, a3 = 0.f;
    for (int di = 0; di < 128; ++di) {
      float m1v = M1[di * 128 + t];
      a0 += tb[0][di] * m1v;
      a1 += tb[1][di] * m1v;
      a2 += tb[2][di] * m1v;
      a3 += tb[3][di] * m1v;
    }
    TG[(r0 + 0) * 128 + t] = a0;
    TG[(r0 + 1) * 128 + t] = a1;
    TG[(r0 + 2) * 128 + t] = a2;
    TG[(r0 + 3) * 128 + t] = a3;
  }
}

// K3: MFMA main. Block = 64 nodes, 4 waves x 16 nodes. B-frags loaded
// directly from global m0frag (coalesced dwordx4, L2-broadcast) — no LDS,
// no barriers.
__global__ __launch_bounds__(256, 2) void k_mainf(
    fp x_L, fp x_y_mask, fp y_mask_L, const int* vidx, const int* tidx,
    fp W_obs, fp b_obs, const float* ws, float* out) {
  const short8* fr = (const short8*)ws;       // m0frag
  const float* c = ws + 49152;
  const float* VG = ws + 74368;
  const float* TG = ws + 139904;
  int tid = threadIdx.x;
  int w = tid >> 6, l = tid & 63;
  int nb = blockIdx.x * 64 + w * 16;
  int b = blockIdx.x >> 6;

  short8 bf[8][4];
#pragma unroll
  for (int fn = 0; fn < 8; ++fn)
#pragma unroll
    for (int ft = 0; ft < 4; ++ft)
      bf[fn][ft] = fr[(fn * 4 + ft) * 64 + l];

  int nodeA = nb + (l & 15);
  float mask = x_y_mask[nodeA];
  float xa = x_L[nodeA];
  float xb = 1.f - mask + y_mask_L[nodeA];
  short8 af[4];
#pragma unroll
  for (int ft = 0; ft < 4; ++ft) {
#pragma unroll
    for (int j = 0; j < 8; ++j) {
      int col = ft * 32 + ((l >> 4) << 3) + j;
      float o = fmaxf(xa * W_obs[col] + xb * W_obs[128 + col] + b_obs[col], 0.f) * mask;
      af[ft][j] = f2bf(o);
    }
  }

  f32x4 acc[8];
#pragma unroll
  for (int fn = 0; fn < 8; ++fn) acc[fn] = (f32x4)(0.f);
#pragma unroll
  for (int fn = 0; fn < 8; ++fn)
#pragma unroll
    for (int ft = 0; ft < 4; ++ft)
      acc[fn] = __builtin_amdgcn_mfma_f32_16x16x32_bf16(af[ft], bf[fn][ft], acc[fn], 0, 0, 0);

  int colbase = l & 15;
  float cv[8];
#pragma unroll
  for (int fn = 0; fn < 8; ++fn) cv[fn] = c[fn * 16 + colbase];
#pragma unroll
  for (int rg = 0; rg < 4; ++rg) {
    int node = nb + ((l >> 4) << 2) + rg;
    float m2 = x_y_mask[node];
    int ti = tidx[node] & 255, vi = vidx[node] & 63;
    const float* tgr = TG + (b * 256 + ti) * 128;
    const float* vgr = VG + (b * 64 + vi) * 128;
    float* orow = out + node * 128;
#pragma unroll
    for (int fn = 0; fn < 8; ++fn) {
      int col = fn * 16 + colbase;
      orow[col] = acc[fn][rg] + cv[fn] + m2 * (tgr[col] + vgr[col]);
    }
  }
}

extern "C" void kernel_launch(void* const* d_in, const int* in_sizes, int n_in,
                              void* d_out, int out_size, void* d_ws, size_t ws_size,
                              hipStream_t stream) {
  const void* P[33];
  {
    int p = 0;
    for (int i = 0; i < 33; ++i) {
      bool isopt = (i == 6 || i == 18 || i == 19);
      if (isopt) {
        if (p < n_in && in_sizes[p] == 1) P[i] = d_in[p++];
        else P[i] = nullptr;
      } else {
        P[i] = (p < n_in) ? d_in[p++] : nullptr;
      }
    }
  }
  fp x_L      = (fp)P[0];
  fp x_y_mask = (fp)P[1];
  fp y_mask_L = (fp)P[2];
  fp x_y_mark = (fp)P[3];
  const int* vidx = (const int*)P[4];
  const int* tidx = (const int*)P[5];
  fp W_obs = (fp)P[7];
  fp b_obs = (fp)P[8];
  fp W_temp = (fp)P[9];
  fp b_temp = (fp)P[10];
  fp var_he_w = (fp)P[11];
  fp Wq = (fp)P[12]; fp bq = (fp)P[13];
  fp Wk = (fp)P[14]; fp bk = (fp)P[15];
  fp Wv = (fp)P[16]; fp bv = (fp)P[17];
  fp thr = (fp)P[18]; fp mc = (fp)P[19];
  fp Pr_w = (fp)P[20]; fp Pr_b = (fp)P[21];
  fp Pi_w = (fp)P[22]; fp Pi_b = (fp)P[23];
  fp Pj_w = (fp)P[24]; fp Pj_b = (fp)P[25];
  fp Pk_w = (fp)P[26]; fp Pk_b = (fp)P[27];
  fp Qr = (fp)P[28]; fp Qi = (fp)P[29];
  fp Qj = (fp)P[30]; fp Qk = (fp)P[31];
  fp fusion_bias = (fp)P[32];

  float* ws = (float*)d_ws;

  hipLaunchKernelGGL(k_setup, dim3(200), dim3(256), 0, stream,
                     Pr_w, Pi_w, Pj_w, Pk_w, Pr_b, Pi_b, Pj_b, Pk_b,
                     Qr, Qi, Qj, Qk, fusion_bias,
                     var_he_w, Wq, bq, Wk, bk, Wv, bv,
                     x_y_mask, vidx, ws);
  hipLaunchKernelGGL(k_mid, dim3(1024), dim3(128), 0, stream,
                     thr, mc, x_y_mark, W_temp, b_temp, ws);
  hipLaunchKernelGGL(k_mainf, dim3(512), dim3(256), 0, stream,
                     x_L, x_y_mask, y_mask_L, vidx, tidx, W_obs, b_obs,
                     ws, (float*)d_out);
}